// Round 14
// baseline (129.469 us; speedup 1.0000x reference)
//
#include <hip/hip_runtime.h>

// X [8192, 256] fp32.  S = X X^T;  out = (S / rowsum(S)) X
// Collapse: out_i = (x_i . M) / den_i,  M = X^T X (256x256).
// den is ill-conditioned -> rows with |den| < TAU get the np-fp32-emulated den
// (sequential ascending-k FMA dot; numpy pairwise rowsum: 128-elem leaves,
// 8-accumulator pattern, perfect binary tree of 64 leaves). Rounds 2-13 pass
// with absmax 16384 < 25559.
// Round-14 (ONE change vs round 13 / session-best r11): out GEMM column-split
// 256 -> 512 blocks, each 32 rows x 128 cols. M L2 traffic is INVARIANT under
// a column split (512 x 128 KB = 256 x 256 KB = 64 MB) while wave parallelism
// doubles (1.5 -> 2.5 blocks/CU) -> exposed M-load latency halves. Live set
// acc[4]+mm[4]+xv ~ 45 VGPRs (no spill). Per-output FMA chain unchanged
// (k-ascending, same j2 order) -> output bit-identical.

#define N 8192
#define D 256
#define TAU 8.0
#define NFMAX 64

// ws layout:
//   0        int    cnt
//   16       int    flagslot[8192]
//   32800    float  M[65536]
//   294944   double den[8192]
//   360480   ushort list[64]
//   360608   float  leaf[64*64]
//   401408   double Tpart[128*256]
//   1048576  float  Mpart[32*65536]
//   16777216 float  XT[256*8192]
#define WS_CNT_OFF    0
#define WS_FLAG_OFF   16
#define WS_M_OFF      32800
#define WS_DEN_OFF    294944
#define WS_LIST_OFF   360480
#define WS_LEAF_OFF   360608
#define WS_TPART_OFF  401408
#define WS_MPART_OFF  1048576
#define WS_XT_OFF     16777216

// ================= kernel A: mtm_part | transpose | colsum+init =============
// (identical to round 13)
__global__ __launch_bounds__(256) void fusedA_k(const float* __restrict__ X,
                                                float* __restrict__ Mpart,
                                                float* __restrict__ XT,
                                                double* __restrict__ Tpart,
                                                int* __restrict__ cnt,
                                                int* __restrict__ flagslot) {
    __shared__ __align__(16) char smem[16896];
    const int tid = threadIdx.x;
    const int bx  = blockIdx.x;

    if (bx < 512) {
        float4* As4 = (float4*)smem;              // 8 KB
        float4* Bs4 = (float4*)(smem + 8192);     // 8 KB
        const int tx = tid & 15;
        const int ty = tid >> 4;
        const int dt = (bx & 3) * 64;
        const int kt = ((bx >> 2) & 3) * 64;
        const int z  = bx >> 4;                   // 0..31
        const int rchunk = z * 256;

        float acc[4][4];
        #pragma unroll
        for (int a = 0; a < 4; ++a)
            #pragma unroll
            for (int b = 0; b < 4; ++b) acc[a][b] = 0.0f;

        for (int c = 0; c < 8; ++c) {
            const int rb = rchunk + c * 32;
            for (int i = tid; i < 512; i += 256) {
                const int rr = i >> 4;
                const int f4 = i & 15;
                const float4* xrow = (const float4*)(X + (size_t)(rb + rr) * D);
                As4[rr * 16 + f4] = xrow[(kt >> 2) + f4];
                Bs4[rr * 16 + f4] = xrow[(dt >> 2) + f4];
            }
            __syncthreads();
            #pragma unroll 8
            for (int r = 0; r < 32; ++r) {
                const float4 a4 = As4[r * 16 + ty];   // 16-lane broadcast
                const float4 b4 = Bs4[r * 16 + tx];   // 2-way alias (free)
                acc[0][0] += a4.x * b4.x; acc[0][1] += a4.x * b4.y; acc[0][2] += a4.x * b4.z; acc[0][3] += a4.x * b4.w;
                acc[1][0] += a4.y * b4.x; acc[1][1] += a4.y * b4.y; acc[1][2] += a4.y * b4.z; acc[1][3] += a4.y * b4.w;
                acc[2][0] += a4.z * b4.x; acc[2][1] += a4.z * b4.y; acc[2][2] += a4.z * b4.z; acc[2][3] += a4.z * b4.w;
                acc[3][0] += a4.w * b4.x; acc[3][1] += a4.w * b4.y; acc[3][2] += a4.w * b4.z; acc[3][3] += a4.w * b4.w;
            }
            __syncthreads();
        }

        float* Mp = Mpart + (size_t)z * 65536;
        #pragma unroll
        for (int a = 0; a < 4; ++a) {
            const int mr = kt + ty * 4 + a;
            *(float4*)(Mp + (size_t)mr * D + dt + tx * 4) =
                make_float4(acc[a][0], acc[a][1], acc[a][2], acc[a][3]);
        }
    } else if (bx < 1024) {
        float (*tile)[65] = (float(*)[65])smem;   // 16.6 KB
        const int b  = bx - 512;
        const int j0 = (b & 127) * 64;
        const int k0 = (b >> 7) * 64;

        const int c4 = tid & 15;
        const int r  = tid >> 4;
        #pragma unroll
        for (int i = 0; i < 4; ++i) {
            const int row = r + i * 16;
            const float4 v = *(const float4*)(X + (size_t)(j0 + row) * D + k0 + c4 * 4);
            tile[row][c4 * 4 + 0] = v.x;
            tile[row][c4 * 4 + 1] = v.y;
            tile[row][c4 * 4 + 2] = v.z;
            tile[row][c4 * 4 + 3] = v.w;
        }
        __syncthreads();

        const int jj4 = tid & 15;
        const int kk  = tid >> 4;
        #pragma unroll
        for (int i = 0; i < 4; ++i) {
            const int k = kk + i * 16;
            float4 o;
            o.x = tile[jj4 * 4 + 0][k];
            o.y = tile[jj4 * 4 + 1][k];
            o.z = tile[jj4 * 4 + 2][k];
            o.w = tile[jj4 * 4 + 3][k];
            *(float4*)(XT + (size_t)(k0 + k) * N + j0 + jj4 * 4) = o;
        }
    } else {
        const int b  = bx - 1024;                 // 0..127
        const int r0 = b * 64;
        double s = 0.0;
        #pragma unroll 8
        for (int r = 0; r < 64; ++r)
            s += (double)X[(size_t)(r0 + r) * D + tid];
        Tpart[b * 256 + tid] = s;

        const int gi = b * 256 + tid;
        if (gi < N) flagslot[gi] = 0;
        if (gi == 0) *cnt = 0;
    }
}

// ================= kernel B: mtm_reduce | den_exact =========================
// (identical to round 13)
__global__ __launch_bounds__(256) void fusedB_k(const float* __restrict__ X,
                                                const float* __restrict__ Mpart,
                                                float* __restrict__ M,
                                                const double* __restrict__ Tpart,
                                                double* __restrict__ den,
                                                int* __restrict__ cnt,
                                                unsigned short* __restrict__ list,
                                                int* __restrict__ flagslot) {
    __shared__ __align__(16) char smem[36864];
    const int tid = threadIdx.x;
    const int bx  = blockIdx.x;

    if (bx < 64) {
        const int e4 = bx * 256 + tid;
        const float4* P4 = (const float4*)Mpart;
        float4 s = make_float4(0.f, 0.f, 0.f, 0.f);
        #pragma unroll 8
        for (int z = 0; z < 32; ++z) {
            const float4 p = P4[(size_t)z * 16384 + e4];
            s.x += p.x; s.y += p.y; s.z += p.z; s.w += p.w;
        }
        ((float4*)M)[e4] = s;
    } else {
        float*  xs    = (float*)smem;                       // 32 KB
        double* Ts    = (double*)(smem + 32768);            // 2 KB
        double (*dpart)[8] = (double(*)[8])(smem + 34816);  // 2 KB

        const int r0 = (bx - 64) * 32;
        {
            const float4* xb = (const float4*)(X + (size_t)r0 * D);
            float4* xs4 = (float4*)xs;
            #pragma unroll
            for (int i = 0; i < 8; ++i) xs4[tid + i * 256] = xb[tid + i * 256];
            double t = 0.0;
            #pragma unroll 8
            for (int b = 0; b < 128; ++b) t += Tpart[b * 256 + tid];
            Ts[tid] = t;
        }
        __syncthreads();

        {
            const int r = tid & 31;
            const int c = tid >> 5;
            double s = 0.0;
            #pragma unroll
            for (int j = 0; j < 32; ++j) {
                const int k = c * 32 + ((j + r) & 31);
                s += (double)xs[r * 256 + k] * Ts[k];
            }
            dpart[r][c] = s;
        }
        __syncthreads();

        if (tid < 32) {
            double s = 0.0;
            #pragma unroll
            for (int c = 0; c < 8; ++c) s += dpart[tid][c];
            const int i = r0 + tid;
            den[i] = s;
            if (fabs(s) < TAU) {
                int p = atomicAdd(cnt, 1);
                if (p < NFMAX) {
                    list[p] = (unsigned short)i;
                    flagslot[i] = p + 1;
                }
            }
        }
    }
}

// ================= kernel C: emu GEMM (0-127) | out GEMM (128-639) ==========
// emu: identical to round 13. out: 512 blocks x (32 rows x 128 cols);
// per-output FMA order unchanged -> bit-identical output.
__global__ __launch_bounds__(256) void emu_out_k(const float* __restrict__ X,
                                                 const float* __restrict__ XT,
                                                 const float* __restrict__ M,
                                                 const double* __restrict__ den,
                                                 const int* __restrict__ cnt,
                                                 const unsigned short* __restrict__ list,
                                                 float* __restrict__ leafbuf,
                                                 float* __restrict__ out) {
    __shared__ __align__(16) char smem[33024];
    const int tid = threadIdx.x;
    const int b   = blockIdx.x;

    if (b < 128) {
        // ---- emu: jc = b&15 (j-chunk of 512), g = b>>4 (row group of 8) ----
        int nflag = *cnt;
        if (nflag > NFMAX) nflag = NFMAX;
        const int groups = (nflag + 7) >> 3;
        const int jc = b & 15;
        const int g  = b >> 4;
        if (g >= groups) return;

        float* xiT = (float*)smem;                  // [256][8]  8 KB
        float* sv  = (float*)(smem + 8192);         // [8][512] 16 KB

        const int base = g * 8;
        #pragma unroll
        for (int q = 0; q < 8; ++q) {
            float v = 0.0f;
            if (base + q < nflag)
                v = X[(size_t)list[base + q] * D + tid];
            xiT[tid * 8 + q] = v;
        }
        __syncthreads();

        const float2* XT2 = (const float2*)XT;      // [256][4096] float2
        const int jb2 = jc * 256 + tid;
        float ax[8], ay[8];
        #pragma unroll
        for (int q = 0; q < 8; ++q) { ax[q] = 0.0f; ay[q] = 0.0f; }

        #pragma unroll 4
        for (int k = 0; k < 256; ++k) {
            const float2 v  = XT2[(size_t)k * (N / 2) + jb2];
            const float4 a0 = *(const float4*)&xiT[k * 8 + 0];   // broadcast
            const float4 a1 = *(const float4*)&xiT[k * 8 + 4];   // broadcast
            ax[0] = fmaf(a0.x, v.x, ax[0]); ay[0] = fmaf(a0.x, v.y, ay[0]);
            ax[1] = fmaf(a0.y, v.x, ax[1]); ay[1] = fmaf(a0.y, v.y, ay[1]);
            ax[2] = fmaf(a0.z, v.x, ax[2]); ay[2] = fmaf(a0.z, v.y, ay[2]);
            ax[3] = fmaf(a0.w, v.x, ax[3]); ay[3] = fmaf(a0.w, v.y, ay[3]);
            ax[4] = fmaf(a1.x, v.x, ax[4]); ay[4] = fmaf(a1.x, v.y, ay[4]);
            ax[5] = fmaf(a1.y, v.x, ax[5]); ay[5] = fmaf(a1.y, v.y, ay[5]);
            ax[6] = fmaf(a1.z, v.x, ax[6]); ay[6] = fmaf(a1.z, v.y, ay[6]);
            ax[7] = fmaf(a1.w, v.x, ax[7]); ay[7] = fmaf(a1.w, v.y, ay[7]);
        }
        #pragma unroll
        for (int q = 0; q < 8; ++q)
            ((float2*)(sv + q * 512))[tid] = make_float2(ax[q], ay[q]);
        __syncthreads();

        if (tid < 32) {
            const int q = tid >> 2, quarter = tid & 3;
            if (base + q < nflag) {
                const float* a = sv + q * 512 + quarter * 128;
                float r0 = a[0], r1 = a[1], r2 = a[2], r3 = a[3];
                float r4 = a[4], r5 = a[5], r6 = a[6], r7 = a[7];
                for (int i2 = 8; i2 < 128; i2 += 8) {
                    r0 += a[i2 + 0]; r1 += a[i2 + 1]; r2 += a[i2 + 2]; r3 += a[i2 + 3];
                    r4 += a[i2 + 4]; r5 += a[i2 + 5]; r6 += a[i2 + 6]; r7 += a[i2 + 7];
                }
                leafbuf[(size_t)(base + q) * 64 + jc * 4 + quarter] =
                    ((r0 + r1) + (r2 + r3)) + ((r4 + r5) + (r6 + r7));
            }
        }
        return;
    }

    // ---- out: 32 rows x 128 cols per block (column-split) ----
    float* xs      = (float*)smem;                  // 32 KB [32][256]
    float* inv_den = (float*)(smem + 32768);        // 128 B

    const int ob = b - 128;                         // 0..511
    const int r0 = (ob >> 1) * 32;
    const int dh = (ob & 1) * 128;
    {
        const float4* xb = (const float4*)(X + (size_t)r0 * D);
        float4* xs4 = (float4*)xs;
        #pragma unroll
        for (int i = 0; i < 8; ++i) xs4[tid + i * 256] = xb[tid + i * 256];
    }
    if (tid < 32) inv_den[tid] = (float)(1.0 / den[r0 + tid]);
    __syncthreads();

    const int d0  = dh + (tid & 31) * 4;            // 32 col-quads cover 128 cols
    const int d04 = d0 >> 2;
    const int rg  = (tid >> 5) * 4;                 // 8 groups x 4 rows = 32 rows
    float4 acc[4];
    #pragma unroll
    for (int i = 0; i < 4; ++i) acc[i] = make_float4(0.f, 0.f, 0.f, 0.f);

    const float4* xs4r = (const float4*)xs;         // [32][64] float4
    const float4* M4   = (const float4*)M;          // [256][64] float4
    #pragma unroll 2
    for (int k4 = 0; k4 < 64; ++k4) {
        float4 mm[4];
        #pragma unroll
        for (int j2 = 0; j2 < 4; ++j2)
            mm[j2] = M4[(size_t)(k4 * 4 + j2) * 64 + d04];
        #pragma unroll
        for (int i = 0; i < 4; ++i) {
            const float4 xv = xs4r[(rg + i) * 64 + k4];   // b128, 2 bcast groups
            acc[i].x += xv.x * mm[0].x; acc[i].y += xv.x * mm[0].y; acc[i].z += xv.x * mm[0].z; acc[i].w += xv.x * mm[0].w;
            acc[i].x += xv.y * mm[1].x; acc[i].y += xv.y * mm[1].y; acc[i].z += xv.y * mm[1].z; acc[i].w += xv.y * mm[1].w;
            acc[i].x += xv.z * mm[2].x; acc[i].y += xv.z * mm[2].y; acc[i].z += xv.z * mm[2].z; acc[i].w += xv.z * mm[2].w;
            acc[i].x += xv.w * mm[3].x; acc[i].y += xv.w * mm[3].y; acc[i].z += xv.w * mm[3].z; acc[i].w += xv.w * mm[3].w;
        }
    }

    #pragma unroll
    for (int i = 0; i < 4; ++i) {
        const int r = rg + i;
        const float inv = inv_den[r];
        float4 o;
        o.x = acc[i].x * inv;
        o.y = acc[i].y * inv;
        o.z = acc[i].z * inv;
        o.w = acc[i].w * inv;
        *(float4*)(out + (size_t)(r0 + r) * D + d0) = o;
    }
}

// ================= kernel D: fixup flagged rows (identical to round 13) =====
__global__ __launch_bounds__(256) void fixup_k(const int* __restrict__ cnt,
                                               const unsigned short* __restrict__ list,
                                               const float* __restrict__ leafbuf,
                                               const double* __restrict__ den,
                                               float* __restrict__ out) {
    int nflag = *cnt;
    if (nflag > NFMAX) nflag = NFMAX;
    const int b = blockIdx.x;
    if (b >= nflag) return;

    const int row = list[b];
    const float* lf = &leafbuf[(size_t)b * 64];
    float t[64];
    #pragma unroll
    for (int l = 0; l < 64; ++l) t[l] = lf[l];
    #pragma unroll
    for (int nn = 32; nn >= 1; nn >>= 1) {
        #pragma unroll
        for (int l = 0; l < nn; ++l) t[l] = t[2 * l] + t[2 * l + 1];
    }
    const double emu = (double)t[0];
    const float ratio = (float)(den[row] * (1.0 / emu));

    const int idx = (int)row * D + threadIdx.x;
    out[idx] = out[idx] * ratio;
}

extern "C" void kernel_launch(void* const* d_in, const int* in_sizes, int n_in,
                              void* d_out, int out_size, void* d_ws, size_t ws_size,
                              hipStream_t stream) {
    const float* X = (const float*)d_in[0];
    float* out = (float*)d_out;

    char* ws = (char*)d_ws;
    int*            cnt      = (int*)(ws + WS_CNT_OFF);
    int*            flagslot = (int*)(ws + WS_FLAG_OFF);
    float*          M        = (float*)(ws + WS_M_OFF);
    double*         den      = (double*)(ws + WS_DEN_OFF);
    unsigned short* list     = (unsigned short*)(ws + WS_LIST_OFF);
    float*          leaf     = (float*)(ws + WS_LEAF_OFF);
    double*         Tpart    = (double*)(ws + WS_TPART_OFF);
    float*          Mpart    = (float*)(ws + WS_MPART_OFF);
    float*          XT       = (float*)(ws + WS_XT_OFF);

    fusedA_k<<<dim3(1152), dim3(256), 0, stream>>>(X, Mpart, XT, Tpart, cnt, flagslot);
    fusedB_k<<<dim3(320),  dim3(256), 0, stream>>>(X, Mpart, M, Tpart, den, cnt, list, flagslot);
    emu_out_k<<<dim3(640), dim3(256), 0, stream>>>(X, XT, M, den, cnt, list, leaf, out);
    fixup_k<<<dim3(NFMAX), dim3(256), 0, stream>>>(cnt, list, leaf, den, out);
}

// Round 15
// 119.283 us; speedup vs baseline: 1.0854x; 1.0854x over previous
//
#include <hip/hip_runtime.h>

// X [8192, 256] fp32.  S = X X^T;  out = (S / rowsum(S)) X
// Collapse: out_i = (x_i . M) / den_i,  M = X^T X (256x256).
// den is ill-conditioned -> rows with |den| < TAU get the np-fp32-emulated den
// (sequential ascending-k FMA dot; numpy pairwise rowsum: 128-elem leaves,
// 8-accumulator pattern, perfect binary tree of 64 leaves). Rounds 2-14 pass
// with absmax 16384 < 25559.
// Round-15: byte-identical REVERT to round 13 (= round 11, 119.65/119.85 us,
// session best). Out-GEMM restructurings all regressed: r9 LDS-staging
// (barrier serialization), r10 acc[8]+xv[8] (spill), r12 spin-fold (critical
// path), r14 column-split (per-wave load:FMA ratio doubled). r11's direct-M
// streaming + b128 xs broadcasts at 256 out-blocks is the empirical optimum.
// Budget at this point: ~46 us harness d_ws/d_out poison fills (268 MB at 80%
// HBM peak, top dispatch, unremovable) + ~12-16 us dispatch gaps + ~58 us
// kernels. Practical floor for this harness.

#define N 8192
#define D 256
#define TAU 8.0
#define NFMAX 64

// ws layout:
//   0        int    cnt
//   16       int    flagslot[8192]
//   32800    float  M[65536]
//   294944   double den[8192]
//   360480   ushort list[64]
//   360608   float  leaf[64*64]
//   401408   double Tpart[128*256]
//   1048576  float  Mpart[32*65536]
//   16777216 float  XT[256*8192]
#define WS_CNT_OFF    0
#define WS_FLAG_OFF   16
#define WS_M_OFF      32800
#define WS_DEN_OFF    294944
#define WS_LIST_OFF   360480
#define WS_LEAF_OFF   360608
#define WS_TPART_OFF  401408
#define WS_MPART_OFF  1048576
#define WS_XT_OFF     16777216

// ================= kernel A: mtm_part | transpose | colsum+init =============
__global__ __launch_bounds__(256) void fusedA_k(const float* __restrict__ X,
                                                float* __restrict__ Mpart,
                                                float* __restrict__ XT,
                                                double* __restrict__ Tpart,
                                                int* __restrict__ cnt,
                                                int* __restrict__ flagslot) {
    __shared__ __align__(16) char smem[16896];
    const int tid = threadIdx.x;
    const int bx  = blockIdx.x;

    if (bx < 512) {
        float4* As4 = (float4*)smem;              // 8 KB
        float4* Bs4 = (float4*)(smem + 8192);     // 8 KB
        const int tx = tid & 15;
        const int ty = tid >> 4;
        const int dt = (bx & 3) * 64;
        const int kt = ((bx >> 2) & 3) * 64;
        const int z  = bx >> 4;                   // 0..31
        const int rchunk = z * 256;

        float acc[4][4];
        #pragma unroll
        for (int a = 0; a < 4; ++a)
            #pragma unroll
            for (int b = 0; b < 4; ++b) acc[a][b] = 0.0f;

        for (int c = 0; c < 8; ++c) {
            const int rb = rchunk + c * 32;
            for (int i = tid; i < 512; i += 256) {
                const int rr = i >> 4;
                const int f4 = i & 15;
                const float4* xrow = (const float4*)(X + (size_t)(rb + rr) * D);
                As4[rr * 16 + f4] = xrow[(kt >> 2) + f4];
                Bs4[rr * 16 + f4] = xrow[(dt >> 2) + f4];
            }
            __syncthreads();
            #pragma unroll 8
            for (int r = 0; r < 32; ++r) {
                const float4 a4 = As4[r * 16 + ty];   // 16-lane broadcast
                const float4 b4 = Bs4[r * 16 + tx];   // 2-way alias (free)
                acc[0][0] += a4.x * b4.x; acc[0][1] += a4.x * b4.y; acc[0][2] += a4.x * b4.z; acc[0][3] += a4.x * b4.w;
                acc[1][0] += a4.y * b4.x; acc[1][1] += a4.y * b4.y; acc[1][2] += a4.y * b4.z; acc[1][3] += a4.y * b4.w;
                acc[2][0] += a4.z * b4.x; acc[2][1] += a4.z * b4.y; acc[2][2] += a4.z * b4.z; acc[2][3] += a4.z * b4.w;
                acc[3][0] += a4.w * b4.x; acc[3][1] += a4.w * b4.y; acc[3][2] += a4.w * b4.z; acc[3][3] += a4.w * b4.w;
            }
            __syncthreads();
        }

        float* Mp = Mpart + (size_t)z * 65536;
        #pragma unroll
        for (int a = 0; a < 4; ++a) {
            const int mr = kt + ty * 4 + a;
            *(float4*)(Mp + (size_t)mr * D + dt + tx * 4) =
                make_float4(acc[a][0], acc[a][1], acc[a][2], acc[a][3]);
        }
    } else if (bx < 1024) {
        float (*tile)[65] = (float(*)[65])smem;   // 16.6 KB
        const int b  = bx - 512;
        const int j0 = (b & 127) * 64;
        const int k0 = (b >> 7) * 64;

        const int c4 = tid & 15;
        const int r  = tid >> 4;
        #pragma unroll
        for (int i = 0; i < 4; ++i) {
            const int row = r + i * 16;
            const float4 v = *(const float4*)(X + (size_t)(j0 + row) * D + k0 + c4 * 4);
            tile[row][c4 * 4 + 0] = v.x;
            tile[row][c4 * 4 + 1] = v.y;
            tile[row][c4 * 4 + 2] = v.z;
            tile[row][c4 * 4 + 3] = v.w;
        }
        __syncthreads();

        const int jj4 = tid & 15;
        const int kk  = tid >> 4;
        #pragma unroll
        for (int i = 0; i < 4; ++i) {
            const int k = kk + i * 16;
            float4 o;
            o.x = tile[jj4 * 4 + 0][k];
            o.y = tile[jj4 * 4 + 1][k];
            o.z = tile[jj4 * 4 + 2][k];
            o.w = tile[jj4 * 4 + 3][k];
            *(float4*)(XT + (size_t)(k0 + k) * N + j0 + jj4 * 4) = o;
        }
    } else {
        const int b  = bx - 1024;                 // 0..127
        const int r0 = b * 64;
        double s = 0.0;
        #pragma unroll 8
        for (int r = 0; r < 64; ++r)
            s += (double)X[(size_t)(r0 + r) * D + tid];
        Tpart[b * 256 + tid] = s;

        const int gi = b * 256 + tid;
        if (gi < N) flagslot[gi] = 0;
        if (gi == 0) *cnt = 0;
    }
}

// ================= kernel B: mtm_reduce | den_exact =========================
__global__ __launch_bounds__(256) void fusedB_k(const float* __restrict__ X,
                                                const float* __restrict__ Mpart,
                                                float* __restrict__ M,
                                                const double* __restrict__ Tpart,
                                                double* __restrict__ den,
                                                int* __restrict__ cnt,
                                                unsigned short* __restrict__ list,
                                                int* __restrict__ flagslot) {
    __shared__ __align__(16) char smem[36864];
    const int tid = threadIdx.x;
    const int bx  = blockIdx.x;

    if (bx < 64) {
        const int e4 = bx * 256 + tid;
        const float4* P4 = (const float4*)Mpart;
        float4 s = make_float4(0.f, 0.f, 0.f, 0.f);
        #pragma unroll 8
        for (int z = 0; z < 32; ++z) {
            const float4 p = P4[(size_t)z * 16384 + e4];
            s.x += p.x; s.y += p.y; s.z += p.z; s.w += p.w;
        }
        ((float4*)M)[e4] = s;
    } else {
        float*  xs    = (float*)smem;                       // 32 KB
        double* Ts    = (double*)(smem + 32768);            // 2 KB
        double (*dpart)[8] = (double(*)[8])(smem + 34816);  // 2 KB

        const int r0 = (bx - 64) * 32;
        {
            const float4* xb = (const float4*)(X + (size_t)r0 * D);
            float4* xs4 = (float4*)xs;
            #pragma unroll
            for (int i = 0; i < 8; ++i) xs4[tid + i * 256] = xb[tid + i * 256];
            double t = 0.0;
            #pragma unroll 8
            for (int b = 0; b < 128; ++b) t += Tpart[b * 256 + tid];
            Ts[tid] = t;
        }
        __syncthreads();

        {
            const int r = tid & 31;
            const int c = tid >> 5;
            double s = 0.0;
            #pragma unroll
            for (int j = 0; j < 32; ++j) {
                const int k = c * 32 + ((j + r) & 31);
                s += (double)xs[r * 256 + k] * Ts[k];
            }
            dpart[r][c] = s;
        }
        __syncthreads();

        if (tid < 32) {
            double s = 0.0;
            #pragma unroll
            for (int c = 0; c < 8; ++c) s += dpart[tid][c];
            const int i = r0 + tid;
            den[i] = s;
            if (fabs(s) < TAU) {
                int p = atomicAdd(cnt, 1);
                if (p < NFMAX) {
                    list[p] = (unsigned short)i;
                    flagslot[i] = p + 1;
                }
            }
        }
    }
}

// ================= kernel C: emu GEMM (blocks 0-127) | out GEMM (128-383) ===
__global__ __launch_bounds__(256) void emu_out_k(const float* __restrict__ X,
                                                 const float* __restrict__ XT,
                                                 const float* __restrict__ M,
                                                 const double* __restrict__ den,
                                                 const int* __restrict__ cnt,
                                                 const unsigned short* __restrict__ list,
                                                 float* __restrict__ leafbuf,
                                                 float* __restrict__ out) {
    __shared__ __align__(16) char smem[33024];
    const int tid = threadIdx.x;
    const int b   = blockIdx.x;

    if (b < 128) {
        // ---- emu: jc = b&15 (j-chunk of 512), g = b>>4 (row group of 8) ----
        int nflag = *cnt;
        if (nflag > NFMAX) nflag = NFMAX;
        const int groups = (nflag + 7) >> 3;
        const int jc = b & 15;
        const int g  = b >> 4;
        if (g >= groups) return;

        float* xiT = (float*)smem;                  // [256][8]  8 KB
        float* sv  = (float*)(smem + 8192);         // [8][512] 16 KB

        const int base = g * 8;
        #pragma unroll
        for (int q = 0; q < 8; ++q) {
            float v = 0.0f;
            if (base + q < nflag)
                v = X[(size_t)list[base + q] * D + tid];
            xiT[tid * 8 + q] = v;
        }
        __syncthreads();

        const float2* XT2 = (const float2*)XT;      // [256][4096] float2
        const int jb2 = jc * 256 + tid;
        float ax[8], ay[8];
        #pragma unroll
        for (int q = 0; q < 8; ++q) { ax[q] = 0.0f; ay[q] = 0.0f; }

        #pragma unroll 4
        for (int k = 0; k < 256; ++k) {
            const float2 v  = XT2[(size_t)k * (N / 2) + jb2];
            const float4 a0 = *(const float4*)&xiT[k * 8 + 0];   // broadcast
            const float4 a1 = *(const float4*)&xiT[k * 8 + 4];   // broadcast
            ax[0] = fmaf(a0.x, v.x, ax[0]); ay[0] = fmaf(a0.x, v.y, ay[0]);
            ax[1] = fmaf(a0.y, v.x, ax[1]); ay[1] = fmaf(a0.y, v.y, ay[1]);
            ax[2] = fmaf(a0.z, v.x, ax[2]); ay[2] = fmaf(a0.z, v.y, ay[2]);
            ax[3] = fmaf(a0.w, v.x, ax[3]); ay[3] = fmaf(a0.w, v.y, ay[3]);
            ax[4] = fmaf(a1.x, v.x, ax[4]); ay[4] = fmaf(a1.x, v.y, ay[4]);
            ax[5] = fmaf(a1.y, v.x, ax[5]); ay[5] = fmaf(a1.y, v.y, ay[5]);
            ax[6] = fmaf(a1.z, v.x, ax[6]); ay[6] = fmaf(a1.z, v.y, ay[6]);
            ax[7] = fmaf(a1.w, v.x, ax[7]); ay[7] = fmaf(a1.w, v.y, ay[7]);
        }
        #pragma unroll
        for (int q = 0; q < 8; ++q)
            ((float2*)(sv + q * 512))[tid] = make_float2(ax[q], ay[q]);
        __syncthreads();

        if (tid < 32) {
            const int q = tid >> 2, quarter = tid & 3;
            if (base + q < nflag) {
                const float* a = sv + q * 512 + quarter * 128;
                float r0 = a[0], r1 = a[1], r2 = a[2], r3 = a[3];
                float r4 = a[4], r5 = a[5], r6 = a[6], r7 = a[7];
                for (int i2 = 8; i2 < 128; i2 += 8) {
                    r0 += a[i2 + 0]; r1 += a[i2 + 1]; r2 += a[i2 + 2]; r3 += a[i2 + 3];
                    r4 += a[i2 + 4]; r5 += a[i2 + 5]; r6 += a[i2 + 6]; r7 += a[i2 + 7];
                }
                leafbuf[(size_t)(base + q) * 64 + jc * 4 + quarter] =
                    ((r0 + r1) + (r2 + r3)) + ((r4 + r5) + (r6 + r7));
            }
        }
        return;
    }

    // ---- out: 32 rows/block, direct M streaming ----
    float* xs      = (float*)smem;                  // 32 KB [32][256]
    float* inv_den = (float*)(smem + 32768);        // 128 B

    const int r0 = (b - 128) * 32;
    {
        const float4* xb = (const float4*)(X + (size_t)r0 * D);
        float4* xs4 = (float4*)xs;
        #pragma unroll
        for (int i = 0; i < 8; ++i) xs4[tid + i * 256] = xb[tid + i * 256];
    }
    if (tid < 32) inv_den[tid] = (float)(1.0 / den[r0 + tid]);
    __syncthreads();

    const int d0  = (tid & 63) * 4;
    const int d04 = d0 >> 2;
    const int rg  = (tid >> 6) * 8;
    float4 acc[8];
    #pragma unroll
    for (int i = 0; i < 8; ++i) acc[i] = make_float4(0.f, 0.f, 0.f, 0.f);

    const float4* xs4r = (const float4*)xs;         // [32][64] float4
    const float4* M4   = (const float4*)M;          // [256][64] float4
    #pragma unroll 2
    for (int k4 = 0; k4 < 64; ++k4) {
        float4 mm[4];
        #pragma unroll
        for (int j2 = 0; j2 < 4; ++j2)
            mm[j2] = M4[(size_t)(k4 * 4 + j2) * 64 + d04];
        #pragma unroll
        for (int i = 0; i < 8; ++i) {
            const float4 xv = xs4r[(rg + i) * 64 + k4];   // broadcast b128
            acc[i].x += xv.x * mm[0].x; acc[i].y += xv.x * mm[0].y; acc[i].z += xv.x * mm[0].z; acc[i].w += xv.x * mm[0].w;
            acc[i].x += xv.y * mm[1].x; acc[i].y += xv.y * mm[1].y; acc[i].z += xv.y * mm[1].z; acc[i].w += xv.y * mm[1].w;
            acc[i].x += xv.z * mm[2].x; acc[i].y += xv.z * mm[2].y; acc[i].z += xv.z * mm[2].z; acc[i].w += xv.z * mm[2].w;
            acc[i].x += xv.w * mm[3].x; acc[i].y += xv.w * mm[3].y; acc[i].z += xv.w * mm[3].z; acc[i].w += xv.w * mm[3].w;
        }
    }

    #pragma unroll
    for (int i = 0; i < 8; ++i) {
        const int r = rg + i;
        const float inv = inv_den[r];
        float4 o;
        o.x = acc[i].x * inv;
        o.y = acc[i].y * inv;
        o.z = acc[i].z * inv;
        o.w = acc[i].w * inv;
        *(float4*)(out + (size_t)(r0 + r) * D + d0) = o;
    }
}

// ================= kernel D: fixup flagged rows =============================
__global__ __launch_bounds__(256) void fixup_k(const int* __restrict__ cnt,
                                               const unsigned short* __restrict__ list,
                                               const float* __restrict__ leafbuf,
                                               const double* __restrict__ den,
                                               float* __restrict__ out) {
    int nflag = *cnt;
    if (nflag > NFMAX) nflag = NFMAX;
    const int b = blockIdx.x;
    if (b >= nflag) return;

    const int row = list[b];
    const float* lf = &leafbuf[(size_t)b * 64];
    float t[64];
    #pragma unroll
    for (int l = 0; l < 64; ++l) t[l] = lf[l];
    #pragma unroll
    for (int nn = 32; nn >= 1; nn >>= 1) {
        #pragma unroll
        for (int l = 0; l < nn; ++l) t[l] = t[2 * l] + t[2 * l + 1];
    }
    const double emu = (double)t[0];
    const float ratio = (float)(den[row] * (1.0 / emu));

    const int idx = (int)row * D + threadIdx.x;
    out[idx] = out[idx] * ratio;
}

extern "C" void kernel_launch(void* const* d_in, const int* in_sizes, int n_in,
                              void* d_out, int out_size, void* d_ws, size_t ws_size,
                              hipStream_t stream) {
    const float* X = (const float*)d_in[0];
    float* out = (float*)d_out;

    char* ws = (char*)d_ws;
    int*            cnt      = (int*)(ws + WS_CNT_OFF);
    int*            flagslot = (int*)(ws + WS_FLAG_OFF);
    float*          M        = (float*)(ws + WS_M_OFF);
    double*         den      = (double*)(ws + WS_DEN_OFF);
    unsigned short* list     = (unsigned short*)(ws + WS_LIST_OFF);
    float*          leaf     = (float*)(ws + WS_LEAF_OFF);
    double*         Tpart    = (double*)(ws + WS_TPART_OFF);
    float*          Mpart    = (float*)(ws + WS_MPART_OFF);
    float*          XT       = (float*)(ws + WS_XT_OFF);

    fusedA_k<<<dim3(1152), dim3(256), 0, stream>>>(X, Mpart, XT, Tpart, cnt, flagslot);
    fusedB_k<<<dim3(320),  dim3(256), 0, stream>>>(X, Mpart, M, Tpart, den, cnt, list, flagslot);
    emu_out_k<<<dim3(384), dim3(256), 0, stream>>>(X, XT, M, den, cnt, list, leaf, out);
    fixup_k<<<dim3(NFMAX), dim3(256), 0, stream>>>(cnt, list, leaf, den, out);
}